// Round 9
// baseline (402.866 us; speedup 1.0000x reference)
//
#include <hip/hip_runtime.h>
#include <hip/hip_fp16.h>

#define FIN 128
#define FH 50
#define HSTRIDE 64
#define MAXNB 1024        // supports n <= 131072 with 128-node buckets
#define BSHIFT 7
#define BSIZE 128
#define CAP 3072          // slab capacity per bucket (mean 2046, ~22 sigma margin)
#define PCHUNK 4096       // edges per partition workgroup
#define SRCMASK 0x01FFFFFFu
#define GMID_BLOCKS 2048  // persistent blocks: 8 blocks/CU x 256 CUs = full occupancy

// -------- CSR build: slab-based two-level counting sort --------

// partition edges into per-bucket slabs: word = (dlocal<<25)|src.
// gcursor[b] (init 0) doubles as reservation cursor and final bucket count.
__global__ __launch_bounds__(256) void partition_kernel(const int* __restrict__ src,
                                                        const int* __restrict__ dst,
                                                        int* __restrict__ gcursor,
                                                        unsigned int* __restrict__ packed,
                                                        int E, int NB) {
    __shared__ int hist[MAXNB];   // phase1: counts; phase3: local cursor
    __shared__ int wbase[MAXNB];
    int t = threadIdx.x;
    int base = blockIdx.x * PCHUNK;
    for (int i = t; i < NB; i += 256) hist[i] = 0;
    __syncthreads();
#pragma unroll 4
    for (int i = 0; i < PCHUNK / 256; i++) {
        int e = base + t + i * 256;
        if (e < E) atomicAdd(&hist[dst[e] >> BSHIFT], 1);
    }
    __syncthreads();
    for (int i = t; i < NB; i += 256) {
        int c = hist[i];
        wbase[i] = c ? atomicAdd(&gcursor[i], c) : 0;
        hist[i] = 0;   // becomes local cursor
    }
    __syncthreads();
#pragma unroll 4
    for (int i = 0; i < PCHUNK / 256; i++) {
        int e = base + t + i * 256;
        if (e < E) {
            unsigned int s = (unsigned int)src[e];
            int d = dst[e];
            int b = d >> BSHIFT;
            int off = atomicAdd(&hist[b], 1);
            packed[(size_t)b * CAP + wbase[b] + off] =
                ((unsigned int)(d & (BSIZE - 1)) << 25) | s;
        }
    }
}

// one WG per bucket: local degree hist -> scan -> rbeg/rend/dinv -> csr fill
__global__ __launch_bounds__(256) void bucket_build_kernel(const unsigned int* __restrict__ packed,
                                                           const int* __restrict__ gcursor,
                                                           int* __restrict__ rbeg,
                                                           int* __restrict__ rend,
                                                           float* __restrict__ dinv,
                                                           int* __restrict__ csr, int n) {
    __shared__ int degl[BSIZE];
    __shared__ int excl[BSIZE];
    __shared__ int lcur[BSIZE];
    int b = blockIdx.x;
    int t = threadIdx.x;
    int nbeg = b << BSHIFT;
    int sbase = b * CAP;
    int cnt = gcursor[b];
    if (t < BSIZE) degl[t] = 0;
    __syncthreads();
    for (int e = t; e < cnt; e += 256)
        atomicAdd(&degl[packed[sbase + e] >> 25], 1);
    __syncthreads();
    int v = (t < BSIZE) ? degl[t] : 0;
    if (t < BSIZE) excl[t] = v;
    __syncthreads();
    for (int off = 1; off < BSIZE; off <<= 1) {
        int add = (t >= off && t < BSIZE) ? excl[t - off] : 0;
        __syncthreads();
        if (t < BSIZE) excl[t] += add;
        __syncthreads();
    }
    if (t < BSIZE) {
        int ex = excl[t] - v;
        int node = nbeg + t;
        if (node < n) {
            rbeg[node] = sbase + ex;
            rend[node] = sbase + ex + v;
            dinv[node] = rsqrtf((float)v + 1.0f);  // +1 = self-loop
        }
        lcur[t] = ex;
    }
    __syncthreads();
    for (int e = t; e < cnt; e += 256) {
        unsigned int w = packed[sbase + e];
        int off = atomicAdd(&lcur[w >> 25], 1);
        csr[sbase + off] = (int)(w & SRCMASK);
    }
}

// -------- dense compute --------

// hs1[row] = fp16((x[row] @ W1) * dinv[row]), stride 64, pad zeroed.
// K split across thread pairs (kh = tid&1) for 2x occupancy; partials
// combined via shfl_xor. Also zeroes sentinel rows n of hs1 and hs2.
__global__ __launch_bounds__(256) void gemm1_kernel(
    const float* __restrict__ x, const float* __restrict__ W,
    const float* __restrict__ dinv, __half* __restrict__ hs1,
    __half* __restrict__ hs2, int n) {
    __shared__ float Ws[FIN * FH];
    int t = threadIdx.x;
    for (int i = t; i < FIN * FH; i += 256) Ws[i] = W[i];
    if (blockIdx.x == 0) {
        if (t < HSTRIDE)           hs1[((size_t)n << 6) + t] = __float2half(0.f);
        else if (t < 2 * HSTRIDE)  hs2[((size_t)n << 6) + (t - HSTRIDE)] = __float2half(0.f);
    }
    __syncthreads();
    int row = blockIdx.x * 128 + (t >> 1);
    int kh = t & 1;
    if (row >= n) return;   // pairs (and waves) cross the boundary together
    float a[FH];
#pragma unroll
    for (int c = 0; c < FH; c++) a[c] = 0.f;
    const float4* xr = (const float4*)(x + (size_t)row * FIN + kh * 64);
#pragma unroll
    for (int k4 = 0; k4 < 16; k4++) {
        float4 xv = xr[k4];
        const float* w0 = &Ws[(kh * 64 + k4 * 4) * FH];
#pragma unroll
        for (int c = 0; c < FH; c++) {
            a[c] = fmaf(xv.x, w0[c], a[c]);
            a[c] = fmaf(xv.y, w0[c + FH], a[c]);
            a[c] = fmaf(xv.z, w0[c + 2 * FH], a[c]);
            a[c] = fmaf(xv.w, w0[c + 3 * FH], a[c]);
        }
    }
#pragma unroll
    for (int c = 0; c < FH; c++) a[c] += __shfl_xor(a[c], 1);
    if (kh == 0) {
        float dv = dinv[row];
        __half2* hp = (__half2*)(hs1 + ((size_t)row << 6));
#pragma unroll
        for (int c = 0; c < HSTRIDE / 2; c++) {
            float lo = (2 * c     < FH) ? a[2 * c] * dv     : 0.f;
            float hi = (2 * c + 1 < FH) ? a[2 * c + 1] * dv : 0.f;
            hp[c] = __floats2half2_rn(lo, hi);
        }
    }
}

// Layer-1 gather fused with layer-2 transform. PERSISTENT at full occupancy:
// 2048 blocks (8/CU), each stages W2 once, waves grid-stride over rows.
// Per row: acc = hs1[self] + sum hs1[csr[...]] (x8 branchless unroll,
// sentinel n); h = relu(dinv*acc + b1); hs2[row] = fp16((h @ W2) * dinv).
__global__ __launch_bounds__(256) void gather_mid_kernel(
    const __half* __restrict__ hs1, const int* __restrict__ rbeg,
    const int* __restrict__ rend, const int* __restrict__ csr,
    const float* __restrict__ dinv, const float* __restrict__ b1,
    const float* __restrict__ W2, __half* __restrict__ hs2, int n) {
    __shared__ float W2s[FH * HSTRIDE];   // [k][c] padded, 12.8 KB
    int t = threadIdx.x;
    for (int i = t; i < FH * HSTRIDE; i += 256) {
        int k = i >> 6, c = i & 63;
        W2s[i] = (c < FH) ? W2[k * FH + c] : 0.f;
    }
    __syncthreads();
    int lane = t & 63;
    int stride = gridDim.x * 4;
    for (int wid = blockIdx.x * 4 + (t >> 6); wid < n; wid += stride) {
        int beg = rbeg[wid];
        int end = rend[wid];
        float acc = __half2float(hs1[((size_t)wid << 6) + lane]);  // self-loop
        for (int base = beg; base < end; base += 64) {
            int rem = end - base;
            int idx = (lane < rem) ? csr[base + lane] : n;   // n = zero sentinel
            int cnt = rem < 64 ? rem : 64;
            for (int j = 0; j < cnt; j += 8) {
                int s0 = __shfl(idx, j);
                int s1 = __shfl(idx, j + 1);
                int s2 = __shfl(idx, j + 2);
                int s3 = __shfl(idx, j + 3);
                int s4 = __shfl(idx, j + 4);
                int s5 = __shfl(idx, j + 5);
                int s6 = __shfl(idx, j + 6);
                int s7 = __shfl(idx, j + 7);
                float v0 = __half2float(hs1[((size_t)s0 << 6) + lane]);
                float v1 = __half2float(hs1[((size_t)s1 << 6) + lane]);
                float v2 = __half2float(hs1[((size_t)s2 << 6) + lane]);
                float v3 = __half2float(hs1[((size_t)s3 << 6) + lane]);
                float v4 = __half2float(hs1[((size_t)s4 << 6) + lane]);
                float v5 = __half2float(hs1[((size_t)s5 << 6) + lane]);
                float v6 = __half2float(hs1[((size_t)s6 << 6) + lane]);
                float v7 = __half2float(hs1[((size_t)s7 << 6) + lane]);
                acc += ((v0 + v1) + (v2 + v3)) + ((v4 + v5) + (v6 + v7));
            }
        }
        float dv = dinv[wid];
        float bb = (lane < FH) ? b1[lane] : 0.f;
        float h = fmaxf(fmaf(dv, acc, bb), 0.f);   // pad lanes: 0
        float s = 0.f;
#pragma unroll
        for (int k = 0; k < FH; k++)
            s = fmaf(__shfl(h, k), W2s[(k << 6) | lane], s);  // pad cols -> 0
        hs2[((size_t)wid << 6) + lane] = __float2half(s * dv);
    }
}

// Layer-2 gather: out[row] = dinv*(hs2[self] + sum hs2[csr]) + b2
__global__ __launch_bounds__(256) void gather_final_kernel(
    const __half* __restrict__ hs2, const int* __restrict__ rbeg,
    const int* __restrict__ rend, const int* __restrict__ csr,
    const float* __restrict__ dinv, const float* __restrict__ b2,
    float* __restrict__ out, int n) {
    int wid = blockIdx.x * 4 + (threadIdx.x >> 6);
    int lane = threadIdx.x & 63;
    if (wid >= n) return;
    int beg = rbeg[wid];
    int end = rend[wid];
    float acc = __half2float(hs2[((size_t)wid << 6) + lane]);  // self-loop term
    for (int base = beg; base < end; base += 64) {
        int rem = end - base;
        int idx = (lane < rem) ? csr[base + lane] : n;   // n = zero sentinel
        int cnt = rem < 64 ? rem : 64;
        for (int j = 0; j < cnt; j += 8) {
            int s0 = __shfl(idx, j);
            int s1 = __shfl(idx, j + 1);
            int s2 = __shfl(idx, j + 2);
            int s3 = __shfl(idx, j + 3);
            int s4 = __shfl(idx, j + 4);
            int s5 = __shfl(idx, j + 5);
            int s6 = __shfl(idx, j + 6);
            int s7 = __shfl(idx, j + 7);
            float v0 = __half2float(hs2[((size_t)s0 << 6) + lane]);
            float v1 = __half2float(hs2[((size_t)s1 << 6) + lane]);
            float v2 = __half2float(hs2[((size_t)s2 << 6) + lane]);
            float v3 = __half2float(hs2[((size_t)s3 << 6) + lane]);
            float v4 = __half2float(hs2[((size_t)s4 << 6) + lane]);
            float v5 = __half2float(hs2[((size_t)s5 << 6) + lane]);
            float v6 = __half2float(hs2[((size_t)s6 << 6) + lane]);
            float v7 = __half2float(hs2[((size_t)s7 << 6) + lane]);
            acc += ((v0 + v1) + (v2 + v3)) + ((v4 + v5) + (v6 + v7));
        }
    }
    if (lane < FH) {
        out[(size_t)wid * FH + lane] = fmaf(dinv[wid], acc, b2[lane]);
    }
}

extern "C" void kernel_launch(void* const* d_in, const int* in_sizes, int n_in,
                              void* d_out, int out_size, void* d_ws, size_t ws_size,
                              hipStream_t stream) {
    const float* x  = (const float*)d_in[0];
    const float* W1 = (const float*)d_in[1];
    const float* b1 = (const float*)d_in[2];
    const float* W2 = (const float*)d_in[3];
    const float* b2 = (const float*)d_in[4];
    const int*   ei = (const int*)d_in[5];

    int n = in_sizes[0] / FIN;   // 100000
    int E = in_sizes[5] / 2;     // 1600000
    const int* src = ei;
    const int* dst = ei + E;
    int NB = (n + BSIZE - 1) >> BSHIFT;   // 782

    char* ws = (char*)d_ws;
    size_t off = 0;
    auto alloc = [&](size_t bytes) {
        void* p = ws + off;
        off = (off + bytes + 511) & ~(size_t)511;
        return p;
    };
    size_t hs_bytes   = (size_t)(n + 1) * HSTRIDE * 2;
    size_t slab_bytes = (size_t)NB * CAP * 4;
    size_t un_bytes   = slab_bytes > hs_bytes ? slab_bytes : hs_bytes;

    int*          gcursor = (int*)alloc((size_t)MAXNB * 4);
    int*          rbeg    = (int*)alloc((size_t)n * 4);
    int*          rend    = (int*)alloc((size_t)n * 4);
    float*        dinv    = (float*)alloc((size_t)n * 4);
    int*          csr     = (int*)alloc(slab_bytes);
    __half*       hs1     = (__half*)alloc(hs_bytes);
    void*         un      = alloc(un_bytes);          // packed, then hs2
    unsigned int* packed  = (unsigned int*)un;        // dead after bucket_build
    __half*       hs2     = (__half*)un;              // live after gemm1
    float*        out     = (float*)d_out;

    hipMemsetAsync(gcursor, 0, (size_t)MAXNB * 4, stream);

    int pChunks = (E + PCHUNK - 1) / PCHUNK;   // 391
    partition_kernel<<<pChunks, 256, 0, stream>>>(src, dst, gcursor, packed, E, NB);
    bucket_build_kernel<<<NB, 256, 0, stream>>>(packed, gcursor, rbeg, rend, dinv, csr, n);

    int g1Blocks = (n + 127) / 128;       // 2 threads per row
    int gatherBlocks = (n + 3) / 4;       // 4 waves/block, 1 wave/row

    gemm1_kernel<<<g1Blocks, 256, 0, stream>>>(x, W1, dinv, hs1, hs2, n);
    gather_mid_kernel<<<GMID_BLOCKS, 256, 0, stream>>>(hs1, rbeg, rend, csr, dinv, b1, W2, hs2, n);
    gather_final_kernel<<<gatherBlocks, 256, 0, stream>>>(hs2, rbeg, rend, csr, dinv, b2, out, n);
}

// Round 10
// 288.993 us; speedup vs baseline: 1.3940x; 1.3940x over previous
//
#include <hip/hip_runtime.h>
#include <hip/hip_fp16.h>

#define FIN 128
#define FH 50
#define HSTRIDE 64
#define MAXNB 1024        // supports n <= 131072 with 128-node buckets
#define BSHIFT 7
#define BSIZE 128
#define CAP 3072          // slab capacity per bucket (mean 2046, ~22 sigma margin)
#define PCHUNK 4096       // edges per partition workgroup
#define SRCMASK 0x01FFFFFFu

// -------- CSR build: slab-based two-level counting sort --------

// partition edges into per-bucket slabs: word = (dlocal<<25)|src.
// gcursor[b] (init 0) doubles as reservation cursor and final bucket count.
__global__ __launch_bounds__(256) void partition_kernel(const int* __restrict__ src,
                                                        const int* __restrict__ dst,
                                                        int* __restrict__ gcursor,
                                                        unsigned int* __restrict__ packed,
                                                        int E, int NB) {
    __shared__ int hist[MAXNB];   // phase1: counts; phase3: local cursor
    __shared__ int wbase[MAXNB];
    int t = threadIdx.x;
    int base = blockIdx.x * PCHUNK;
    for (int i = t; i < NB; i += 256) hist[i] = 0;
    __syncthreads();
#pragma unroll 4
    for (int i = 0; i < PCHUNK / 256; i++) {
        int e = base + t + i * 256;
        if (e < E) atomicAdd(&hist[dst[e] >> BSHIFT], 1);
    }
    __syncthreads();
    for (int i = t; i < NB; i += 256) {
        int c = hist[i];
        wbase[i] = c ? atomicAdd(&gcursor[i], c) : 0;
        hist[i] = 0;   // becomes local cursor
    }
    __syncthreads();
#pragma unroll 4
    for (int i = 0; i < PCHUNK / 256; i++) {
        int e = base + t + i * 256;
        if (e < E) {
            unsigned int s = (unsigned int)src[e];
            int d = dst[e];
            int b = d >> BSHIFT;
            int off = atomicAdd(&hist[b], 1);
            packed[(size_t)b * CAP + wbase[b] + off] =
                ((unsigned int)(d & (BSIZE - 1)) << 25) | s;
        }
    }
}

// one WG per bucket: local degree hist -> scan -> rbeg/rend/dinv -> csr fill
__global__ __launch_bounds__(256) void bucket_build_kernel(const unsigned int* __restrict__ packed,
                                                           const int* __restrict__ gcursor,
                                                           int* __restrict__ rbeg,
                                                           int* __restrict__ rend,
                                                           float* __restrict__ dinv,
                                                           int* __restrict__ csr, int n) {
    __shared__ int degl[BSIZE];
    __shared__ int excl[BSIZE];
    __shared__ int lcur[BSIZE];
    int b = blockIdx.x;
    int t = threadIdx.x;
    int nbeg = b << BSHIFT;
    int sbase = b * CAP;
    int cnt = gcursor[b];
    if (t < BSIZE) degl[t] = 0;
    __syncthreads();
    for (int e = t; e < cnt; e += 256)
        atomicAdd(&degl[packed[sbase + e] >> 25], 1);
    __syncthreads();
    int v = (t < BSIZE) ? degl[t] : 0;
    if (t < BSIZE) excl[t] = v;
    __syncthreads();
    for (int off = 1; off < BSIZE; off <<= 1) {
        int add = (t >= off && t < BSIZE) ? excl[t - off] : 0;
        __syncthreads();
        if (t < BSIZE) excl[t] += add;
        __syncthreads();
    }
    if (t < BSIZE) {
        int ex = excl[t] - v;
        int node = nbeg + t;
        if (node < n) {
            rbeg[node] = sbase + ex;
            rend[node] = sbase + ex + v;
            dinv[node] = rsqrtf((float)v + 1.0f);  // +1 = self-loop
        }
        lcur[t] = ex;
    }
    __syncthreads();
    for (int e = t; e < cnt; e += 256) {
        unsigned int w = packed[sbase + e];
        int off = atomicAdd(&lcur[w >> 25], 1);
        csr[sbase + off] = (int)(w & SRCMASK);
    }
}

// -------- dense compute --------

// hs1[row] = fp16((x[row] @ W1) * dinv[row]), stride 64, pad zeroed.
// K split across thread pairs (kh = tid&1) for 2x grid; partials combined
// via shfl_xor. Also zeroes sentinel rows n of hs1 and hs2.
__global__ __launch_bounds__(256) void gemm1_kernel(
    const float* __restrict__ x, const float* __restrict__ W,
    const float* __restrict__ dinv, __half* __restrict__ hs1,
    __half* __restrict__ hs2, int n) {
    __shared__ float Ws[FIN * FH];
    int t = threadIdx.x;
    for (int i = t; i < FIN * FH; i += 256) Ws[i] = W[i];
    if (blockIdx.x == 0) {
        if (t < HSTRIDE)           hs1[((size_t)n << 6) + t] = __float2half(0.f);
        else if (t < 2 * HSTRIDE)  hs2[((size_t)n << 6) + (t - HSTRIDE)] = __float2half(0.f);
    }
    __syncthreads();
    int row = blockIdx.x * 128 + (t >> 1);
    int kh = t & 1;
    if (row >= n) return;   // pairs (and waves) cross the boundary together
    float a[FH];
#pragma unroll
    for (int c = 0; c < FH; c++) a[c] = 0.f;
    const float4* xr = (const float4*)(x + (size_t)row * FIN + kh * 64);
#pragma unroll
    for (int k4 = 0; k4 < 16; k4++) {
        float4 xv = xr[k4];
        const float* w0 = &Ws[(kh * 64 + k4 * 4) * FH];
#pragma unroll
        for (int c = 0; c < FH; c++) {
            a[c] = fmaf(xv.x, w0[c], a[c]);
            a[c] = fmaf(xv.y, w0[c + FH], a[c]);
            a[c] = fmaf(xv.z, w0[c + 2 * FH], a[c]);
            a[c] = fmaf(xv.w, w0[c + 3 * FH], a[c]);
        }
    }
#pragma unroll
    for (int c = 0; c < FH; c++) a[c] += __shfl_xor(a[c], 1);
    if (kh == 0) {
        float dv = dinv[row];
        __half2* hp = (__half2*)(hs1 + ((size_t)row << 6));
#pragma unroll
        for (int c = 0; c < HSTRIDE / 2; c++) {
            float lo = (2 * c     < FH) ? a[2 * c] * dv     : 0.f;
            float hi = (2 * c + 1 < FH) ? a[2 * c + 1] * dv : 0.f;
            hp[c] = __floats2half2_rn(lo, hi);
        }
    }
}

// hs2[row] = fp16((h1[row] @ W2) * dinv[row]). Four threads per row, each
// computes 14 output cols (c0 = 0/14/26/38; overlap compute, even-aligned
// half2 stores of 7/6/6/6). Grid 4x vs thread-per-row -> ~6 blocks/CU.
// Pad cols 50..63 of regular rows stay garbage (never read as output; only
// lanes >= FH in gather see them and those lanes are never stored).
__global__ __launch_bounds__(256) void gemm2_kernel(
    const float* __restrict__ h1, const float* __restrict__ W,
    const float* __restrict__ dinv, __half* __restrict__ hs2, int n) {
    __shared__ float Ws[FH * FH];
    int t = threadIdx.x;
    for (int i = t; i < FH * FH; i += 256) Ws[i] = W[i];
    __syncthreads();
    int row = blockIdx.x * 64 + (t >> 2);
    int q = t & 3;
    if (row >= n) return;   // no shuffles below; divergent exit is safe
    int c0 = q ? (12 * q + 2) : 0;        // 0,14,26,38
    const float* xp = h1 + (size_t)row * FH;
    float xr[FH];
#pragma unroll
    for (int k = 0; k < FH; k++) xr[k] = xp[k];
    float a[14];
#pragma unroll
    for (int c = 0; c < 14; c++) a[c] = 0.f;
    for (int k = 0; k < FH; k++) {
        float xv = xr[k];
        const float* w = &Ws[k * FH + c0];
#pragma unroll
        for (int c = 0; c < 14; c++) a[c] = fmaf(xv, w[c], a[c]);
    }
    float dv = dinv[row];
    __half2* hp = (__half2*)(hs2 + ((size_t)row << 6) + c0);
    int nst = q ? 6 : 7;
    for (int j = 0; j < nst; j++)
        hp[j] = __floats2half2_rn(a[2 * j] * dv, a[2 * j + 1] * dv);
}

// one wave per dst row: acc = hs[self] + sum hs[csr[...]]; x16 branchless
// unroll (lanes >= rem hold sentinel n whose hs row is zero), 16 gather
// loads in flight per vmcnt batch. out = relu?(dinv*acc + b), fp32.
__global__ __launch_bounds__(256) void gather_kernel(
    const __half* __restrict__ hs, const int* __restrict__ rbeg,
    const int* __restrict__ rend, const int* __restrict__ csr,
    const float* __restrict__ dinv, const float* __restrict__ b,
    float* __restrict__ out, int n, int do_relu) {
    int wid = blockIdx.x * 4 + (threadIdx.x >> 6);
    int lane = threadIdx.x & 63;
    if (wid >= n) return;
    int beg = rbeg[wid];
    int end = rend[wid];
    float acc = __half2float(hs[((size_t)wid << 6) + lane]);  // self-loop term
    for (int base = beg; base < end; base += 64) {
        int rem = end - base;
        int idx = (lane < rem) ? csr[base + lane] : n;   // n = zero sentinel
        int cnt = rem < 64 ? rem : 64;
        for (int j = 0; j < cnt; j += 16) {
            float v[16];
#pragma unroll
            for (int u = 0; u < 16; u++) {
                int s = __shfl(idx, j + u);
                v[u] = __half2float(hs[((size_t)s << 6) + lane]);
            }
            float s01 = (v[0] + v[1]) + (v[2] + v[3]);
            float s23 = (v[4] + v[5]) + (v[6] + v[7]);
            float s45 = (v[8] + v[9]) + (v[10] + v[11]);
            float s67 = (v[12] + v[13]) + (v[14] + v[15]);
            acc += (s01 + s23) + (s45 + s67);
        }
    }
    if (lane < FH) {
        float o = fmaf(dinv[wid], acc, b[lane]);
        if (do_relu) o = fmaxf(o, 0.f);
        out[(size_t)wid * FH + lane] = o;
    }
}

extern "C" void kernel_launch(void* const* d_in, const int* in_sizes, int n_in,
                              void* d_out, int out_size, void* d_ws, size_t ws_size,
                              hipStream_t stream) {
    const float* x  = (const float*)d_in[0];
    const float* W1 = (const float*)d_in[1];
    const float* b1 = (const float*)d_in[2];
    const float* W2 = (const float*)d_in[3];
    const float* b2 = (const float*)d_in[4];
    const int*   ei = (const int*)d_in[5];

    int n = in_sizes[0] / FIN;   // 100000
    int E = in_sizes[5] / 2;     // 1600000
    const int* src = ei;
    const int* dst = ei + E;
    int NB = (n + BSIZE - 1) >> BSHIFT;   // 782

    char* ws = (char*)d_ws;
    size_t off = 0;
    auto alloc = [&](size_t bytes) {
        void* p = ws + off;
        off = (off + bytes + 511) & ~(size_t)511;
        return p;
    };
    size_t hs_bytes   = (size_t)(n + 1) * HSTRIDE * 2;
    size_t slab_bytes = (size_t)NB * CAP * 4;
    size_t un_bytes   = slab_bytes > hs_bytes ? slab_bytes : hs_bytes;

    int*          gcursor = (int*)alloc((size_t)MAXNB * 4);
    int*          rbeg    = (int*)alloc((size_t)n * 4);
    int*          rend    = (int*)alloc((size_t)n * 4);
    float*        dinv    = (float*)alloc((size_t)n * 4);
    int*          csr     = (int*)alloc(slab_bytes);
    __half*       hs1     = (__half*)alloc(hs_bytes);
    void*         un      = alloc(un_bytes);          // packed, then hs2
    unsigned int* packed  = (unsigned int*)un;        // dead after bucket_build
    __half*       hs2     = (__half*)un;              // live after gemm1
    float*        out     = (float*)d_out;            // also layer-1 h buffer

    hipMemsetAsync(gcursor, 0, (size_t)MAXNB * 4, stream);

    int pChunks = (E + PCHUNK - 1) / PCHUNK;   // 391
    partition_kernel<<<pChunks, 256, 0, stream>>>(src, dst, gcursor, packed, E, NB);
    bucket_build_kernel<<<NB, 256, 0, stream>>>(packed, gcursor, rbeg, rend, dinv, csr, n);

    int g1Blocks = (n + 127) / 128;       // 2 threads per row
    int g2Blocks = (n + 63) / 64;         // 4 threads per row
    int gatherBlocks = (n + 3) / 4;       // 4 waves/block, 1 wave/row

    gemm1_kernel<<<g1Blocks, 256, 0, stream>>>(x, W1, dinv, hs1, hs2, n);
    gather_kernel<<<gatherBlocks, 256, 0, stream>>>(hs1, rbeg, rend, csr, dinv, b1, out, n, 1);
    gemm2_kernel<<<g2Blocks, 256, 0, stream>>>(out, W2, dinv, hs2, n);
    gather_kernel<<<gatherBlocks, 256, 0, stream>>>(hs2, rbeg, rend, csr, dinv, b2, out, n, 0);
}